// Round 1
// 1108.521 us; speedup vs baseline: 1.0001x; 1.0001x over previous
//
#include <hip/hip_runtime.h>

#define D   256    // HIDDEN
#define B   1024   // NUM_GRAPHS
#define K2  512    // 2*D
#define G4  1024   // 4*D
#define NSPLIT 8   // attention splits per graph (1 chunk of <=64 rows per block)
#define NZ     4   // K-splits for gates gemm

__device__ __forceinline__ float sigm(float x)   { return 1.f / (1.f + __expf(-x)); }
__device__ __forceinline__ float tanh_f(float x) { return 1.f - 2.f / (1.f + __expf(2.f * x)); }

// ---------------- weight prep: Wc = [W_ih[:,:D] + W_hh | W_ih[:,D:]], bc = b_ih + b_hh
__global__ void prep_weights(const float* __restrict__ W_ih, const float* __restrict__ W_hh,
                             const float* __restrict__ b_ih, const float* __restrict__ b_hh,
                             float* __restrict__ Wc, float* __restrict__ bc) {
    int idx = blockIdx.x * blockDim.x + threadIdx.x;
    if (idx < G4 * K2) {
        int j = idx >> 9;
        int k = idx & 511;
        float w = W_ih[idx];
        if (k < D) w += W_hh[j * D + k];
        Wc[idx] = w;
    }
    if (idx < G4) bc[idx] = b_ih[idx] + b_hh[idx];
}

// ---------------- segment bounds via binary search (segment_ids sorted)
__global__ void seg_bounds(const int* __restrict__ seg, int* __restrict__ out, int N) {
    int b = blockIdx.x * blockDim.x + threadIdx.x;
    if (b > B) return;
    if (b == B) { out[B] = N; return; }
    int lo = 0, hi = N;
    while (lo < hi) {
        int mid = (lo + hi) >> 1;
        if (seg[mid] < b) lo = mid + 1; else hi = mid;
    }
    out[b] = lo;
}

// ---------------- gates GEMM: 128x128 tile, 8x8 microtile, K-split via blockIdx.z.
// Cp[z][M,N] = A[:, z*ksz:(z+1)*ksz] * Bm^T   (no bias; bias folded into lstm_step)
// LDS reads: 4x ds_read_b128 per 64 FMA (vs 2 per 16 in the 4x4 version) -> half the
// LDS-pipe wall. Micro rows/cols interleaved (t*4+(i&3)+64*(i>>2)) so b128 reads are
// <=2-way bank-aliased (free) instead of 4-way.
__global__ __launch_bounds__(256) void gemm128(const float* __restrict__ A,
                                               const float* __restrict__ Bm,
                                               float* __restrict__ Cp,
                                               int M, int N, int K, int ksz) {
    __shared__ float As[16][132];
    __shared__ float Bs[16][132];
    int tid = threadIdx.x;
    int tx = tid & 15, ty = tid >> 4;
    int m0 = blockIdx.y << 7, n0 = blockIdx.x << 7;
    int klo = blockIdx.z * ksz;
    float* C = Cp + (size_t)blockIdx.z * M * N;
    int lr = tid >> 1;            // 0..127 tile row
    int lk = (tid & 1) << 3;      // 0 or 8
    const float* pa = A  + (size_t)(m0 + lr) * K + klo + lk;
    const float* pb = Bm + (size_t)(n0 + lr) * K + klo + lk;
    float4 a0 = *(const float4*)pa, a1 = *(const float4*)(pa + 4);
    float4 b0 = *(const float4*)pb, b1 = *(const float4*)(pb + 4);
    float acc[8][8] = {};
    for (int k0 = 0; k0 < ksz; k0 += 16) {
        As[lk + 0][lr] = a0.x; As[lk + 1][lr] = a0.y; As[lk + 2][lr] = a0.z; As[lk + 3][lr] = a0.w;
        As[lk + 4][lr] = a1.x; As[lk + 5][lr] = a1.y; As[lk + 6][lr] = a1.z; As[lk + 7][lr] = a1.w;
        Bs[lk + 0][lr] = b0.x; Bs[lk + 1][lr] = b0.y; Bs[lk + 2][lr] = b0.z; Bs[lk + 3][lr] = b0.w;
        Bs[lk + 4][lr] = b1.x; Bs[lk + 5][lr] = b1.y; Bs[lk + 6][lr] = b1.z; Bs[lk + 7][lr] = b1.w;
        __syncthreads();
        if (k0 + 16 < ksz) {      // register prefetch of next k-tile
            a0 = *(const float4*)(pa + k0 + 16); a1 = *(const float4*)(pa + k0 + 20);
            b0 = *(const float4*)(pb + k0 + 16); b1 = *(const float4*)(pb + k0 + 20);
        }
#pragma unroll
        for (int kk = 0; kk < 16; ++kk) {
            float4 alo = *(const float4*)&As[kk][ty * 4];
            float4 ahi = *(const float4*)&As[kk][ty * 4 + 64];
            float4 blo = *(const float4*)&Bs[kk][tx * 4];
            float4 bhi = *(const float4*)&Bs[kk][tx * 4 + 64];
            float ar[8] = {alo.x, alo.y, alo.z, alo.w, ahi.x, ahi.y, ahi.z, ahi.w};
            float br[8] = {blo.x, blo.y, blo.z, blo.w, bhi.x, bhi.y, bhi.z, bhi.w};
#pragma unroll
            for (int i = 0; i < 8; ++i)
#pragma unroll
                for (int j = 0; j < 8; ++j)
                    acc[i][j] = fmaf(ar[i], br[j], acc[i][j]);
        }
        __syncthreads();
    }
#pragma unroll
    for (int i = 0; i < 8; ++i) {
        int m = m0 + ty * 4 + (i & 3) + ((i >> 2) << 6);
        float4 o0 = make_float4(acc[i][0], acc[i][1], acc[i][2], acc[i][3]);
        float4 o1 = make_float4(acc[i][4], acc[i][5], acc[i][6], acc[i][7]);
        *(float4*)(C + (size_t)m * N + n0 + tx * 4)      = o0;
        *(float4*)(C + (size_t)m * N + n0 + tx * 4 + 64) = o1;
    }
}

// ---------------- legacy 64x64 gemm (kept for the final fc layer, z=1 path)
__global__ __launch_bounds__(256) void gemm_nt(const float* __restrict__ A,
                                               const float* __restrict__ Bm,
                                               const float* __restrict__ bias,
                                               float* __restrict__ Cp,
                                               int M, int N, int K, int ksz) {
    __shared__ float As[16][68];
    __shared__ float Bs[16][68];
    int tid = threadIdx.x;
    int tx = tid & 15, ty = tid >> 4;
    int m0 = blockIdx.y << 6, n0 = blockIdx.x << 6;
    int z = blockIdx.z;
    int klo = z * ksz;
    float* C = Cp + (size_t)z * M * N;
    int lr = tid >> 2;
    int lk = (tid & 3) << 2;
    const float* pa = A  + (size_t)(m0 + lr) * K + klo + lk;
    const float* pb = Bm + (size_t)(n0 + lr) * K + klo + lk;
    float4 a4 = *(const float4*)pa;
    float4 b4 = *(const float4*)pb;
    float acc[4][4] = {};
    for (int k0 = 0; k0 < ksz; k0 += 16) {
        As[lk + 0][lr] = a4.x; As[lk + 1][lr] = a4.y; As[lk + 2][lr] = a4.z; As[lk + 3][lr] = a4.w;
        Bs[lk + 0][lr] = b4.x; Bs[lk + 1][lr] = b4.y; Bs[lk + 2][lr] = b4.z; Bs[lk + 3][lr] = b4.w;
        __syncthreads();
        if (k0 + 16 < ksz) {
            a4 = *(const float4*)(pa + k0 + 16);
            b4 = *(const float4*)(pb + k0 + 16);
        }
#pragma unroll
        for (int kk = 0; kk < 16; ++kk) {
            float a0 = As[kk][ty * 4 + 0], a1 = As[kk][ty * 4 + 1];
            float a2 = As[kk][ty * 4 + 2], a3 = As[kk][ty * 4 + 3];
            float b0 = Bs[kk][tx * 4 + 0], b1 = Bs[kk][tx * 4 + 1];
            float b2 = Bs[kk][tx * 4 + 2], b3 = Bs[kk][tx * 4 + 3];
            acc[0][0] += a0 * b0; acc[0][1] += a0 * b1; acc[0][2] += a0 * b2; acc[0][3] += a0 * b3;
            acc[1][0] += a1 * b0; acc[1][1] += a1 * b1; acc[1][2] += a1 * b2; acc[1][3] += a1 * b3;
            acc[2][0] += a2 * b0; acc[2][1] += a2 * b1; acc[2][2] += a2 * b2; acc[2][3] += a2 * b3;
            acc[3][0] += a3 * b0; acc[3][1] += a3 * b1; acc[3][2] += a3 * b2; acc[3][3] += a3 * b3;
        }
        __syncthreads();
    }
    int n = n0 + tx * 4;
    float bx = 0.f, by = 0.f, bz = 0.f, bw = 0.f;
    if (z == 0 && bias) { bx = bias[n]; by = bias[n + 1]; bz = bias[n + 2]; bw = bias[n + 3]; }
#pragma unroll
    for (int i = 0; i < 4; ++i) {
        int m = m0 + ty * 4 + i;
        float4 o;
        o.x = acc[i][0] + bx; o.y = acc[i][1] + by; o.z = acc[i][2] + bz; o.w = acc[i][3] + bw;
        *(float4*)(C + (size_t)m * N + n) = o;
    }
}

// ---------------- LSTM cell, once per graph (de-duplicated from attn prologue).
// gates = bc + sum_z gpart[z];  h -> xcat[:, :D];  c ping-pong in cbuf.
__global__ __launch_bounds__(256) void lstm_step(const float* __restrict__ gpart,
                                                 const float* __restrict__ bc,
                                                 float* __restrict__ cbuf,
                                                 float* __restrict__ xcat,
                                                 int it) {
    int b = blockIdx.x, j = threadIdx.x;
    float gi = bc[j], gf = bc[D + j], gg = bc[2 * D + j], go = bc[3 * D + j];
    if (it > 0) {
        const float* g = gpart + (size_t)b * G4;
#pragma unroll
        for (int s = 0; s < NZ; ++s, g += (size_t)B * G4) {
            gi += g[j]; gf += g[D + j]; gg += g[2 * D + j]; go += g[3 * D + j];
        }
    }
    float cold = (it == 0) ? 0.f : cbuf[(size_t)(it & 1) * B * D + (size_t)b * D + j];
    float cn = sigm(gf) * cold + sigm(gi) * tanh_f(gg);
    float hn = sigm(go) * tanh_f(cn);
    cbuf[(size_t)((it & 1) ^ 1) * B * D + (size_t)b * D + j] = cn;
    xcat[(size_t)b * K2 + j] = hn;
}

// ---------------- split attention: 8 splits/graph -> one 64-row chunk per block
// (no serial chunk chain: loads issue once, blocks pipeline across the CU).
// Wave w owns rows w*16..+15 (lane l holds dims 4l..4l+3); LDS-transpose dot
// reduction; shuffle softmax; partial (m, l, acc) per split for the combiner.
__global__ __launch_bounds__(256) void attn8(const float* __restrict__ feat,
                                             const int* __restrict__ segs,
                                             const float* __restrict__ xcat,
                                             float* __restrict__ pm,
                                             float* __restrict__ pl,
                                             float* __restrict__ pacc) {
    int blk = blockIdx.x, tid = threadIdx.x;
    int b = blk >> 3, sp = blk & 7;
    int wave = tid >> 6, lane = tid & 63;

    __shared__ float pd[4][16][69];
    __shared__ float esh[2][64];
    __shared__ float wsh[2][64];
    __shared__ float acc_sh[4][D];

    float4 q4 = *(const float4*)(xcat + (size_t)b * K2 + lane * 4);

    int s0 = segs[b], e0 = segs[b + 1];
    int len = e0 - s0, span = (len + NSPLIT - 1) >> 3;
    int s = s0 + sp * span;
    int e = min(s + span, e0);

    float m = -3.0e38f, l = 0.f;
    float4 acc = make_float4(0.f, 0.f, 0.f, 0.f);
    int par = 0;

    for (int base = s; base < e; base += 64, par ^= 1) {   // normally exactly one pass
        float4 f[16];
#pragma unroll
        for (int t = 0; t < 16; ++t) {
            int n = base + wave * 16 + t;
            f[t] = (n < e) ? *(const float4*)(feat + (size_t)n * D + lane * 4)
                           : make_float4(0.f, 0.f, 0.f, 0.f);
        }
#pragma unroll
        for (int t = 0; t < 16; ++t)
            pd[wave][t][lane] = f[t].x * q4.x + f[t].y * q4.y + f[t].z * q4.z + f[t].w * q4.w;
        int tt = lane & 15, sg = lane >> 4;
        float r = 0.f;
#pragma unroll
        for (int i = 0; i < 16; ++i) r += pd[wave][tt][sg * 16 + i];
        r += __shfl_xor(r, 16, 64);
        r += __shfl_xor(r, 32, 64);
        if (lane < 16) esh[par][wave * 16 + lane] = r;
        __syncthreads();
        float ev = (base + lane < e) ? esh[par][lane] : -3.0e38f;
        float cm = ev;
#pragma unroll
        for (int off = 32; off > 0; off >>= 1) cm = fmaxf(cm, __shfl_xor(cm, off, 64));
        float mc = fmaxf(m, cm);
        float wl = __expf(ev - mc);
        float ws = wl;
#pragma unroll
        for (int off = 32; off > 0; off >>= 1) ws += __shfl_xor(ws, off, 64);
        float sc = __expf(m - mc);
        l = l * sc + ws;
        m = mc;
        acc.x *= sc; acc.y *= sc; acc.z *= sc; acc.w *= sc;
        wsh[par][lane] = wl;          // identical values from all waves: benign
#pragma unroll
        for (int t = 0; t < 16; ++t) {
            float w = wsh[par][wave * 16 + t];
            acc.x = fmaf(w, f[t].x, acc.x);
            acc.y = fmaf(w, f[t].y, acc.y);
            acc.z = fmaf(w, f[t].z, acc.z);
            acc.w = fmaf(w, f[t].w, acc.w);
        }
    }
    acc_sh[wave][lane * 4 + 0] = acc.x;
    acc_sh[wave][lane * 4 + 1] = acc.y;
    acc_sh[wave][lane * 4 + 2] = acc.z;
    acc_sh[wave][lane * 4 + 3] = acc.w;
    __syncthreads();
    float r4 = acc_sh[0][tid] + acc_sh[1][tid] + acc_sh[2][tid] + acc_sh[3][tid];
    pacc[(size_t)blk * D + tid] = r4;
    if (tid == 0) { pm[blk] = m; pl[blk] = l; }
}

// ---------------- combine 8 split partials -> readout -> xcat[:, D:2D]
__global__ __launch_bounds__(256) void attn_combine8(const float* __restrict__ pm,
                                                     const float* __restrict__ pl,
                                                     const float* __restrict__ pacc,
                                                     float* __restrict__ xcat) {
    int b = blockIdx.x, tid = threadIdx.x;
    float M = -3.0e38f;
#pragma unroll
    for (int s = 0; s < NSPLIT; ++s) M = fmaxf(M, pm[NSPLIT * b + s]);
    float L = 0.f, R = 0.f;
#pragma unroll
    for (int s = 0; s < NSPLIT; ++s) {
        float w = __expf(pm[NSPLIT * b + s] - M);
        L += pl[NSPLIT * b + s] * w;
        R += pacc[(size_t)(NSPLIT * b + s) * D + tid] * w;
    }
    xcat[(size_t)b * K2 + D + tid] = (L > 0.f) ? R / L : 0.f;
}

extern "C" void kernel_launch(void* const* d_in, const int* in_sizes, int n_in,
                              void* d_out, int out_size, void* d_ws, size_t ws_size,
                              hipStream_t stream) {
    const float* feat   = (const float*)d_in[0];
    const int*   segids = (const int*)d_in[1];
    const float* W_ih   = (const float*)d_in[2];
    const float* W_hh   = (const float*)d_in[3];
    const float* b_ih   = (const float*)d_in[4];
    const float* b_hh   = (const float*)d_in[5];
    const float* fc_w   = (const float*)d_in[6];
    const float* fc_b   = (const float*)d_in[7];
    float* out = (float*)d_out;
    int N = in_sizes[1];   // N_NODES

    // workspace carve-up (floats): ~31.5 MB total
    float* Wc    = (float*)d_ws;                     // [G4][K2]        524288
    float* bc    = Wc + (size_t)G4 * K2;             // [G4]            1024
    float* xcat  = bc + G4;                          // [B][K2]         524288
    float* cbuf  = xcat + (size_t)B * K2;            // [2][B][D]       524288
    float* gpart = cbuf + (size_t)2 * B * D;         // [NZ][B][G4]     4194304
    float* pm    = gpart + (size_t)NZ * B * G4;      // [8B]            8192
    float* pl    = pm + NSPLIT * B;                  // [8B]            8192
    float* pacc  = pl + NSPLIT * B;                  // [8B][D]         2097152
    int*   segs  = (int*)(pacc + (size_t)NSPLIT * B * D); // [B+1]

    hipLaunchKernelGGL(prep_weights, dim3((G4 * K2 + 255) / 256), dim3(256), 0, stream,
                       W_ih, W_hh, b_ih, b_hh, Wc, bc);
    hipLaunchKernelGGL(seg_bounds, dim3((B + 1 + 255) / 256), dim3(256), 0, stream,
                       segids, segs, N);

    for (int it = 0; it < 6; ++it) {
        if (it > 0)   // it==0: q_star=0 -> gates = bc, handled in lstm_step
            hipLaunchKernelGGL(gemm128, dim3(G4 / 128, B / 128, NZ), dim3(256), 0, stream,
                               xcat, Wc, gpart, B, G4, K2, K2 / NZ);
        hipLaunchKernelGGL(lstm_step, dim3(B), dim3(256), 0, stream,
                           gpart, bc, cbuf, xcat, it);
        hipLaunchKernelGGL(attn8, dim3(NSPLIT * B), dim3(256), 0, stream,
                           feat, segs, xcat, pm, pl, pacc);
        hipLaunchKernelGGL(attn_combine8, dim3(B), dim3(256), 0, stream, pm, pl, pacc, xcat);
    }
    hipLaunchKernelGGL(gemm_nt, dim3(D / 64, B / 64, 1), dim3(256), 0, stream,
                       xcat, fc_w, fc_b, out, B, D, K2, K2);
}

// Round 2
// 935.019 us; speedup vs baseline: 1.1857x; 1.1856x over previous
//
#include <hip/hip_runtime.h>
#include <hip/hip_fp16.h>

#define D   256    // HIDDEN
#define B   1024   // NUM_GRAPHS
#define K2  512    // 2*D
#define G4  1024   // 4*D
#define NSPLIT 8   // attention splits per graph (1 chunk of <=64 rows per block)
#define NZ     4   // K-splits for gates gemm

__device__ __forceinline__ float sigm(float x)   { return 1.f / (1.f + __expf(-x)); }
__device__ __forceinline__ float tanh_f(float x) { return 1.f - 2.f / (1.f + __expf(2.f * x)); }

// ---------------- weight prep: Wc = [W_ih[:,:D] + W_hh | W_ih[:,D:]], bc = b_ih + b_hh
__global__ void prep_weights(const float* __restrict__ W_ih, const float* __restrict__ W_hh,
                             const float* __restrict__ b_ih, const float* __restrict__ b_hh,
                             float* __restrict__ Wc, float* __restrict__ bc) {
    int idx = blockIdx.x * blockDim.x + threadIdx.x;
    if (idx < G4 * K2) {
        int j = idx >> 9;
        int k = idx & 511;
        float w = W_ih[idx];
        if (k < D) w += W_hh[j * D + k];
        Wc[idx] = w;
    }
    if (idx < G4) bc[idx] = b_ih[idx] + b_hh[idx];
}

// ---------------- segment bounds via binary search (segment_ids sorted)
__global__ void seg_bounds(const int* __restrict__ seg, int* __restrict__ out, int N) {
    int b = blockIdx.x * blockDim.x + threadIdx.x;
    if (b > B) return;
    if (b == B) { out[B] = N; return; }
    int lo = 0, hi = N;
    while (lo < hi) {
        int mid = (lo + hi) >> 1;
        if (seg[mid] < b) lo = mid + 1; else hi = mid;
    }
    out[b] = lo;
}

// ---------------- gates GEMM: 128x128 tile, 8x8 microtile, K-split via blockIdx.z.
__global__ __launch_bounds__(256) void gemm128(const float* __restrict__ A,
                                               const float* __restrict__ Bm,
                                               float* __restrict__ Cp,
                                               int M, int N, int K, int ksz) {
    __shared__ float As[16][132];
    __shared__ float Bs[16][132];
    int tid = threadIdx.x;
    int tx = tid & 15, ty = tid >> 4;
    int m0 = blockIdx.y << 7, n0 = blockIdx.x << 7;
    int klo = blockIdx.z * ksz;
    float* C = Cp + (size_t)blockIdx.z * M * N;
    int lr = tid >> 1;            // 0..127 tile row
    int lk = (tid & 1) << 3;      // 0 or 8
    const float* pa = A  + (size_t)(m0 + lr) * K + klo + lk;
    const float* pb = Bm + (size_t)(n0 + lr) * K + klo + lk;
    float4 a0 = *(const float4*)pa, a1 = *(const float4*)(pa + 4);
    float4 b0 = *(const float4*)pb, b1 = *(const float4*)(pb + 4);
    float acc[8][8] = {};
    for (int k0 = 0; k0 < ksz; k0 += 16) {
        As[lk + 0][lr] = a0.x; As[lk + 1][lr] = a0.y; As[lk + 2][lr] = a0.z; As[lk + 3][lr] = a0.w;
        As[lk + 4][lr] = a1.x; As[lk + 5][lr] = a1.y; As[lk + 6][lr] = a1.z; As[lk + 7][lr] = a1.w;
        Bs[lk + 0][lr] = b0.x; Bs[lk + 1][lr] = b0.y; Bs[lk + 2][lr] = b0.z; Bs[lk + 3][lr] = b0.w;
        Bs[lk + 4][lr] = b1.x; Bs[lk + 5][lr] = b1.y; Bs[lk + 6][lr] = b1.z; Bs[lk + 7][lr] = b1.w;
        __syncthreads();
        if (k0 + 16 < ksz) {      // register prefetch of next k-tile
            a0 = *(const float4*)(pa + k0 + 16); a1 = *(const float4*)(pa + k0 + 20);
            b0 = *(const float4*)(pb + k0 + 16); b1 = *(const float4*)(pb + k0 + 20);
        }
#pragma unroll
        for (int kk = 0; kk < 16; ++kk) {
            float4 alo = *(const float4*)&As[kk][ty * 4];
            float4 ahi = *(const float4*)&As[kk][ty * 4 + 64];
            float4 blo = *(const float4*)&Bs[kk][tx * 4];
            float4 bhi = *(const float4*)&Bs[kk][tx * 4 + 64];
            float ar[8] = {alo.x, alo.y, alo.z, alo.w, ahi.x, ahi.y, ahi.z, ahi.w};
            float br[8] = {blo.x, blo.y, blo.z, blo.w, bhi.x, bhi.y, bhi.z, bhi.w};
#pragma unroll
            for (int i = 0; i < 8; ++i)
#pragma unroll
                for (int j = 0; j < 8; ++j)
                    acc[i][j] = fmaf(ar[i], br[j], acc[i][j]);
        }
        __syncthreads();
    }
#pragma unroll
    for (int i = 0; i < 8; ++i) {
        int m = m0 + ty * 4 + (i & 3) + ((i >> 2) << 6);
        float4 o0 = make_float4(acc[i][0], acc[i][1], acc[i][2], acc[i][3]);
        float4 o1 = make_float4(acc[i][4], acc[i][5], acc[i][6], acc[i][7]);
        *(float4*)(C + (size_t)m * N + n0 + tx * 4)      = o0;
        *(float4*)(C + (size_t)m * N + n0 + tx * 4 + 64) = o1;
    }
}

// ---------------- legacy 64x64 gemm (final fc layer)
__global__ __launch_bounds__(256) void gemm_nt(const float* __restrict__ A,
                                               const float* __restrict__ Bm,
                                               const float* __restrict__ bias,
                                               float* __restrict__ Cp,
                                               int M, int N, int K, int ksz) {
    __shared__ float As[16][68];
    __shared__ float Bs[16][68];
    int tid = threadIdx.x;
    int tx = tid & 15, ty = tid >> 4;
    int m0 = blockIdx.y << 6, n0 = blockIdx.x << 6;
    int z = blockIdx.z;
    int klo = z * ksz;
    float* C = Cp + (size_t)z * M * N;
    int lr = tid >> 2;
    int lk = (tid & 3) << 2;
    const float* pa = A  + (size_t)(m0 + lr) * K + klo + lk;
    const float* pb = Bm + (size_t)(n0 + lr) * K + klo + lk;
    float4 a4 = *(const float4*)pa;
    float4 b4 = *(const float4*)pb;
    float acc[4][4] = {};
    for (int k0 = 0; k0 < ksz; k0 += 16) {
        As[lk + 0][lr] = a4.x; As[lk + 1][lr] = a4.y; As[lk + 2][lr] = a4.z; As[lk + 3][lr] = a4.w;
        Bs[lk + 0][lr] = b4.x; Bs[lk + 1][lr] = b4.y; Bs[lk + 2][lr] = b4.z; Bs[lk + 3][lr] = b4.w;
        __syncthreads();
        if (k0 + 16 < ksz) {
            a4 = *(const float4*)(pa + k0 + 16);
            b4 = *(const float4*)(pb + k0 + 16);
        }
#pragma unroll
        for (int kk = 0; kk < 16; ++kk) {
            float a0 = As[kk][ty * 4 + 0], a1 = As[kk][ty * 4 + 1];
            float a2 = As[kk][ty * 4 + 2], a3 = As[kk][ty * 4 + 3];
            float b0 = Bs[kk][tx * 4 + 0], b1 = Bs[kk][tx * 4 + 1];
            float b2 = Bs[kk][tx * 4 + 2], b3 = Bs[kk][tx * 4 + 3];
            acc[0][0] += a0 * b0; acc[0][1] += a0 * b1; acc[0][2] += a0 * b2; acc[0][3] += a0 * b3;
            acc[1][0] += a1 * b0; acc[1][1] += a1 * b1; acc[1][2] += a1 * b2; acc[1][3] += a1 * b3;
            acc[2][0] += a2 * b0; acc[2][1] += a2 * b1; acc[2][2] += a2 * b2; acc[2][3] += a2 * b3;
            acc[3][0] += a3 * b0; acc[3][1] += a3 * b1; acc[3][2] += a3 * b2; acc[3][3] += a3 * b3;
        }
        __syncthreads();
    }
    int n = n0 + tx * 4;
    float bx = 0.f, by = 0.f, bz = 0.f, bw = 0.f;
    if (z == 0 && bias) { bx = bias[n]; by = bias[n + 1]; bz = bias[n + 2]; bw = bias[n + 3]; }
#pragma unroll
    for (int i = 0; i < 4; ++i) {
        int m = m0 + ty * 4 + i;
        float4 o;
        o.x = acc[i][0] + bx; o.y = acc[i][1] + by; o.z = acc[i][2] + bz; o.w = acc[i][3] + bw;
        *(float4*)(C + (size_t)m * N + n) = o;
    }
}

// ---------------- LSTM cell, once per graph
__global__ __launch_bounds__(256) void lstm_step(const float* __restrict__ gpart,
                                                 const float* __restrict__ bc,
                                                 float* __restrict__ cbuf,
                                                 float* __restrict__ xcat,
                                                 int it) {
    int b = blockIdx.x, j = threadIdx.x;
    float gi = bc[j], gf = bc[D + j], gg = bc[2 * D + j], go = bc[3 * D + j];
    if (it > 0) {
        const float* g = gpart + (size_t)b * G4;
#pragma unroll
        for (int s = 0; s < NZ; ++s, g += (size_t)B * G4) {
            gi += g[j]; gf += g[D + j]; gg += g[2 * D + j]; go += g[3 * D + j];
        }
    }
    float cold = (it == 0) ? 0.f : cbuf[(size_t)(it & 1) * B * D + (size_t)b * D + j];
    float cn = sigm(gf) * cold + sigm(gi) * tanh_f(gg);
    float hn = sigm(go) * tanh_f(cn);
    cbuf[(size_t)((it & 1) ^ 1) * B * D + (size_t)b * D + j] = cn;
    xcat[(size_t)b * K2 + j] = hn;
}

// ---------------- split attention, templated on feat precision path.
// MODE 0 (iter 0): read fp32 feat, compute exactly as before, AND write each row
//                  back as fp16 into feat16 (splits partition rows -> written once).
// MODE 1 (iters 1-5): read fp16 feat16 (half the HBM bytes), convert to fp32.
// Dots/softmax/accumulate identical fp32 math in both modes.
template <int MODE>
__global__ __launch_bounds__(256) void attn8(const float* __restrict__ feat,
                                             __half* __restrict__ feat16,
                                             const int* __restrict__ segs,
                                             const float* __restrict__ xcat,
                                             float* __restrict__ pm,
                                             float* __restrict__ pl,
                                             float* __restrict__ pacc) {
    int blk = blockIdx.x, tid = threadIdx.x;
    int b = blk >> 3, sp = blk & 7;
    int wave = tid >> 6, lane = tid & 63;

    __shared__ float pd[4][16][69];
    __shared__ float esh[2][64];
    __shared__ float wsh[2][64];
    __shared__ float acc_sh[4][D];

    float4 q4 = *(const float4*)(xcat + (size_t)b * K2 + lane * 4);

    int s0 = segs[b], e0 = segs[b + 1];
    int len = e0 - s0, span = (len + NSPLIT - 1) >> 3;
    int s = s0 + sp * span;
    int e = min(s + span, e0);

    float m = -3.0e38f, l = 0.f;
    float4 acc = make_float4(0.f, 0.f, 0.f, 0.f);
    int par = 0;

    for (int base = s; base < e; base += 64, par ^= 1) {   // normally exactly one pass
        float4 f[16];
        if (MODE == 0) {
#pragma unroll
            for (int t = 0; t < 16; ++t) {
                int n = base + wave * 16 + t;
                f[t] = (n < e) ? *(const float4*)(feat + (size_t)n * D + lane * 4)
                               : make_float4(0.f, 0.f, 0.f, 0.f);
            }
            // write fp16 shadow copy (guard: only rows owned by this split)
#pragma unroll
            for (int t = 0; t < 16; ++t) {
                int n = base + wave * 16 + t;
                if (n < e) {
                    __half2 h0 = __floats2half2_rn(f[t].x, f[t].y);
                    __half2 h1 = __floats2half2_rn(f[t].z, f[t].w);
                    uint2 raw;
                    raw.x = *(unsigned int*)&h0;
                    raw.y = *(unsigned int*)&h1;
                    *(uint2*)(feat16 + (size_t)n * D + lane * 4) = raw;
                }
            }
        } else {
#pragma unroll
            for (int t = 0; t < 16; ++t) {
                int n = base + wave * 16 + t;
                uint2 raw = (n < e) ? *(const uint2*)(feat16 + (size_t)n * D + lane * 4)
                                    : make_uint2(0u, 0u);
                float2 f01 = __half22float2(*(__half2*)&raw.x);
                float2 f23 = __half22float2(*(__half2*)&raw.y);
                f[t] = make_float4(f01.x, f01.y, f23.x, f23.y);
            }
        }
#pragma unroll
        for (int t = 0; t < 16; ++t)
            pd[wave][t][lane] = f[t].x * q4.x + f[t].y * q4.y + f[t].z * q4.z + f[t].w * q4.w;
        int tt = lane & 15, sg = lane >> 4;
        float r = 0.f;
#pragma unroll
        for (int i = 0; i < 16; ++i) r += pd[wave][tt][sg * 16 + i];
        r += __shfl_xor(r, 16, 64);
        r += __shfl_xor(r, 32, 64);
        if (lane < 16) esh[par][wave * 16 + lane] = r;
        __syncthreads();
        float ev = (base + lane < e) ? esh[par][lane] : -3.0e38f;
        float cm = ev;
#pragma unroll
        for (int off = 32; off > 0; off >>= 1) cm = fmaxf(cm, __shfl_xor(cm, off, 64));
        float mc = fmaxf(m, cm);
        float wl = __expf(ev - mc);
        float ws = wl;
#pragma unroll
        for (int off = 32; off > 0; off >>= 1) ws += __shfl_xor(ws, off, 64);
        float sc = __expf(m - mc);
        l = l * sc + ws;
        m = mc;
        acc.x *= sc; acc.y *= sc; acc.z *= sc; acc.w *= sc;
        wsh[par][lane] = wl;          // identical values from all waves: benign
#pragma unroll
        for (int t = 0; t < 16; ++t) {
            float w = wsh[par][wave * 16 + t];
            acc.x = fmaf(w, f[t].x, acc.x);
            acc.y = fmaf(w, f[t].y, acc.y);
            acc.z = fmaf(w, f[t].z, acc.z);
            acc.w = fmaf(w, f[t].w, acc.w);
        }
    }
    acc_sh[wave][lane * 4 + 0] = acc.x;
    acc_sh[wave][lane * 4 + 1] = acc.y;
    acc_sh[wave][lane * 4 + 2] = acc.z;
    acc_sh[wave][lane * 4 + 3] = acc.w;
    __syncthreads();
    float r4 = acc_sh[0][tid] + acc_sh[1][tid] + acc_sh[2][tid] + acc_sh[3][tid];
    pacc[(size_t)blk * D + tid] = r4;
    if (tid == 0) { pm[blk] = m; pl[blk] = l; }
}

// ---------------- combine 8 split partials -> readout -> xcat[:, D:2D]
__global__ __launch_bounds__(256) void attn_combine8(const float* __restrict__ pm,
                                                     const float* __restrict__ pl,
                                                     const float* __restrict__ pacc,
                                                     float* __restrict__ xcat) {
    int b = blockIdx.x, tid = threadIdx.x;
    float M = -3.0e38f;
#pragma unroll
    for (int s = 0; s < NSPLIT; ++s) M = fmaxf(M, pm[NSPLIT * b + s]);
    float L = 0.f, R = 0.f;
#pragma unroll
    for (int s = 0; s < NSPLIT; ++s) {
        float w = __expf(pm[NSPLIT * b + s] - M);
        L += pl[NSPLIT * b + s] * w;
        R += pacc[(size_t)(NSPLIT * b + s) * D + tid] * w;
    }
    xcat[(size_t)b * K2 + D + tid] = (L > 0.f) ? R / L : 0.f;
}

extern "C" void kernel_launch(void* const* d_in, const int* in_sizes, int n_in,
                              void* d_out, int out_size, void* d_ws, size_t ws_size,
                              hipStream_t stream) {
    const float* feat   = (const float*)d_in[0];
    const int*   segids = (const int*)d_in[1];
    const float* W_ih   = (const float*)d_in[2];
    const float* W_hh   = (const float*)d_in[3];
    const float* b_ih   = (const float*)d_in[4];
    const float* b_hh   = (const float*)d_in[5];
    const float* fc_w   = (const float*)d_in[6];
    const float* fc_b   = (const float*)d_in[7];
    float* out = (float*)d_out;
    int N = in_sizes[1];   // N_NODES

    // workspace carve-up (floats): ~31.5 MB + 205 MB fp16 feat shadow
    float* Wc    = (float*)d_ws;                     // [G4][K2]        524288
    float* bc    = Wc + (size_t)G4 * K2;             // [G4]            1024
    float* xcat  = bc + G4;                          // [B][K2]         524288
    float* cbuf  = xcat + (size_t)B * K2;            // [2][B][D]       524288
    float* gpart = cbuf + (size_t)2 * B * D;         // [NZ][B][G4]     4194304
    float* pm    = gpart + (size_t)NZ * B * G4;      // [8B]            8192
    float* pl    = pm + NSPLIT * B;                  // [8B]            8192
    float* pacc  = pl + NSPLIT * B;                  // [8B][D]         2097152
    int*   segs  = (int*)(pacc + (size_t)NSPLIT * B * D); // [B+1]
    // align fp16 shadow to 16 B
    size_t off = ((size_t)(segs + (B + 2)) - (size_t)d_ws + 15) & ~(size_t)15;
    __half* feat16 = (__half*)((char*)d_ws + off);   // [N][D] halves   ~205 MB

    hipLaunchKernelGGL(prep_weights, dim3((G4 * K2 + 255) / 256), dim3(256), 0, stream,
                       W_ih, W_hh, b_ih, b_hh, Wc, bc);
    hipLaunchKernelGGL(seg_bounds, dim3((B + 1 + 255) / 256), dim3(256), 0, stream,
                       segids, segs, N);

    for (int it = 0; it < 6; ++it) {
        if (it > 0)   // it==0: q_star=0 -> gates = bc, handled in lstm_step
            hipLaunchKernelGGL(gemm128, dim3(G4 / 128, B / 128, NZ), dim3(256), 0, stream,
                               xcat, Wc, gpart, B, G4, K2, K2 / NZ);
        hipLaunchKernelGGL(lstm_step, dim3(B), dim3(256), 0, stream,
                           gpart, bc, cbuf, xcat, it);
        if (it == 0)
            hipLaunchKernelGGL((attn8<0>), dim3(NSPLIT * B), dim3(256), 0, stream,
                               feat, feat16, segs, xcat, pm, pl, pacc);
        else
            hipLaunchKernelGGL((attn8<1>), dim3(NSPLIT * B), dim3(256), 0, stream,
                               feat, feat16, segs, xcat, pm, pl, pacc);
        hipLaunchKernelGGL(attn_combine8, dim3(B), dim3(256), 0, stream, pm, pl, pacc, xcat);
    }
    hipLaunchKernelGGL(gemm_nt, dim3(D / 64, B / 64, 1), dim3(256), 0, stream,
                       xcat, fc_w, fc_b, out, B, D, K2, K2);
}